// Round 1
// baseline (118.150 us; speedup 1.0000x reference)
//
#include <hip/hip_runtime.h>

// Problem constants (match the JAX reference)
constexpr int Bv  = 4;
constexpr int NXv = 432;
constexpr int NYv = 496;
constexpr int Cv  = 64;
constexpr int PLANE = NYv * NXv;          // 214272 cells per (b) grid
constexpr int GRID_CELLS = Bv * PLANE;    // 857088 cells per tensor
constexpr int NX4 = NXv / 4;              // 108 float4-groups per row

// ---------------------------------------------------------------------------
// Kernel 1: scatter voxel row index n into map[b*PLANE + y*NX + x].
// coords row layout: (b, z, y, x), z == 0. Indices are unique -> no races.
// ---------------------------------------------------------------------------
__global__ void build_map_kernel(const int* __restrict__ coords, int n,
                                 int* __restrict__ map) {
    int i = blockIdx.x * blockDim.x + threadIdx.x;
    if (i >= n) return;
    const int4 c = reinterpret_cast<const int4*>(coords)[i]; // x=b, y=z, z=y, w=x
    map[(c.x * NYv + c.z) * NXv + c.w] = i;
}

// ---------------------------------------------------------------------------
// Kernel 2: gather. One thread per 4 consecutive x-cells of one (b, y) row.
// Loops over all 64 channels, writing one float4 per channel plane.
// Output is written fully (zeros where map == -1) -> no prior memset of d_out.
// ---------------------------------------------------------------------------
__global__ void gather_bev_kernel(const int* __restrict__ map,
                                  const float* __restrict__ feats,
                                  float* __restrict__ out) {
    int tid = blockIdx.x * blockDim.x + threadIdx.x; // 0 .. GRID_CELLS/4 - 1
    if (tid >= GRID_CELLS / 4) return;
    int x4   = tid % NX4;
    int rest = tid / NX4;
    int y    = rest % NYv;
    int b    = rest / NYv;

    int cellbase = (b * NYv + y) * NXv + x4 * 4;
    const int4 m = *reinterpret_cast<const int4*>(map + cellbase);

    float* outp = out + (size_t)b * Cv * PLANE + (size_t)y * NXv + x4 * 4;

    #pragma unroll 8
    for (int c = 0; c < Cv; ++c) {
        float4 v;
        v.x = (m.x >= 0) ? feats[(size_t)m.x * Cv + c] : 0.0f;
        v.y = (m.y >= 0) ? feats[(size_t)m.y * Cv + c] : 0.0f;
        v.z = (m.z >= 0) ? feats[(size_t)m.z * Cv + c] : 0.0f;
        v.w = (m.w >= 0) ? feats[(size_t)m.w * Cv + c] : 0.0f;
        *reinterpret_cast<float4*>(outp + (size_t)c * PLANE) = v;
    }
}

// ---------------------------------------------------------------------------
// Fallback (only if ws too small): direct scatter after zeroing output.
// Thread per (voxel, channel).
// ---------------------------------------------------------------------------
__global__ void direct_scatter_kernel(const float* __restrict__ feats,
                                      const int* __restrict__ coords, int n,
                                      float* __restrict__ out) {
    int i = blockIdx.x * blockDim.x + threadIdx.x;
    if (i >= n * Cv) return;
    int v = i >> 6;        // voxel index
    int c = i & 63;        // channel
    int b = coords[v * 4 + 0];
    int y = coords[v * 4 + 2];
    int x = coords[v * 4 + 3];
    out[((size_t)(b * Cv + c) * NYv + y) * NXv + x] = feats[(size_t)v * Cv + c];
}

extern "C" void kernel_launch(void* const* d_in, const int* in_sizes, int n_in,
                              void* d_out, int out_size, void* d_ws, size_t ws_size,
                              hipStream_t stream) {
    const float* t_feats  = (const float*)d_in[0];
    const int*   t_coords = (const int*)d_in[1];
    const float* s_feats  = (const float*)d_in[2];
    const int*   s_coords = (const int*)d_in[3];
    float* out = (float*)d_out;

    const int NT = in_sizes[0] / Cv;  // 16384 template voxels
    const int NS = in_sizes[2] / Cv;  // 65536 search voxels
    const size_t half = (size_t)out_size / 2; // elements per output tensor

    const size_t map_bytes = 2ull * GRID_CELLS * sizeof(int);

    if (ws_size >= map_bytes) {
        int* map_t = (int*)d_ws;
        int* map_s = map_t + GRID_CELLS;

        // init both maps to -1 (0xFF bytes)
        hipMemsetAsync(d_ws, 0xFF, map_bytes, stream);

        build_map_kernel<<<(NT + 255) / 256, 256, 0, stream>>>(t_coords, NT, map_t);
        build_map_kernel<<<(NS + 255) / 256, 256, 0, stream>>>(s_coords, NS, map_s);

        const int gthreads = GRID_CELLS / 4;               // 214272
        const int gblocks  = (gthreads + 255) / 256;       // 837
        gather_bev_kernel<<<gblocks, 256, 0, stream>>>(map_t, t_feats, out);
        gather_bev_kernel<<<gblocks, 256, 0, stream>>>(map_s, s_feats, out + half);
    } else {
        // Fallback: zero output, then scatter directly.
        hipMemsetAsync(d_out, 0, (size_t)out_size * sizeof(float), stream);
        direct_scatter_kernel<<<(NT * Cv + 255) / 256, 256, 0, stream>>>(
            t_feats, t_coords, NT, out);
        direct_scatter_kernel<<<(NS * Cv + 255) / 256, 256, 0, stream>>>(
            s_feats, s_coords, NS, out + half);
    }
}

// Round 2
// 104.505 us; speedup vs baseline: 1.1306x; 1.1306x over previous
//
#include <hip/hip_runtime.h>

// Problem constants (match the JAX reference)
constexpr int Bv  = 4;
constexpr int NXv = 432;
constexpr int NYv = 496;
constexpr int Cv  = 64;
constexpr int PLANE = NYv * NXv;          // 214272 cells per (b) grid
constexpr int GRID_CELLS = Bv * PLANE;    // 857088 cells per tensor
constexpr int PER_TENSOR_T4 = GRID_CELLS / 4;  // 214272 threads per tensor (4 cells each)

// ---------------------------------------------------------------------------
// Kernel 1: fused scatter of voxel row index (i+1) into map for both tensors.
// map default is 0 (single memset covers map + zero_row). Indices unique.
// coords row layout: (b, z, y, x), z == 0.
// ---------------------------------------------------------------------------
__global__ void build_all_kernel(const int* __restrict__ t_coords, int nt,
                                 const int* __restrict__ s_coords, int ns,
                                 int* __restrict__ map) {
    int i = blockIdx.x * blockDim.x + threadIdx.x;
    if (i < nt) {
        const int4 c = reinterpret_cast<const int4*>(t_coords)[i]; // b,z,y,x
        map[(c.x * NYv + c.z) * NXv + c.w] = i + 1;
    } else if (i < nt + ns) {
        int j = i - nt;
        const int4 c = reinterpret_cast<const int4*>(s_coords)[j];
        map[GRID_CELLS + (c.x * NYv + c.z) * NXv + c.w] = j + 1;
    }
}

// ---------------------------------------------------------------------------
// Kernel 2: fused gather for BOTH output tensors.
// One thread per 4 consecutive x-cells. Per thread: pick 4 source-row
// pointers (feature row or shared zero row) once, then an unconditional
// float4-load / float4-store loop over channels (transposing 4x4 in regs).
// Tensor split and batch split both land on exact wave boundaries.
// ---------------------------------------------------------------------------
__global__ __launch_bounds__(256) void gather_all_kernel(
        const int* __restrict__ map,
        const float* __restrict__ t_feats,
        const float* __restrict__ s_feats,
        const float* __restrict__ zero_row,
        float* __restrict__ out, size_t half) {
    int tid = blockIdx.x * blockDim.x + threadIdx.x;
    const int which = (tid >= PER_TENSOR_T4) ? 1 : 0;  // wave-uniform (214272 % 64 == 0)
    const int lid = tid - which * PER_TENSOR_T4;

    const int*   mp    = map + which * GRID_CELLS;
    const float* feats = which ? s_feats : t_feats;
    float*       obase = out + (which ? half : 0);

    const int g = lid * 4;                 // first cell index (b*PLANE + y*NX + x)
    const int b = lid / (PLANE / 4);       // wave-uniform (53568 % 64 == 0)

    const int4 m = *reinterpret_cast<const int4*>(mp + g);

    const float* p0 = (m.x > 0) ? feats + (size_t)(m.x - 1) * Cv : zero_row;
    const float* p1 = (m.y > 0) ? feats + (size_t)(m.y - 1) * Cv : zero_row;
    const float* p2 = (m.z > 0) ? feats + (size_t)(m.z - 1) * Cv : zero_row;
    const float* p3 = (m.w > 0) ? feats + (size_t)(m.w - 1) * Cv : zero_row;

    // out[b][c][y][x]: offset = g + b*(Cv-1)*PLANE + c*PLANE
    float* o = obase + g + (size_t)b * (Cv - 1) * PLANE;

    #pragma unroll 4
    for (int cg = 0; cg < Cv / 4; ++cg) {
        const float4 a = *reinterpret_cast<const float4*>(p0 + cg * 4);
        const float4 e = *reinterpret_cast<const float4*>(p1 + cg * 4);
        const float4 f = *reinterpret_cast<const float4*>(p2 + cg * 4);
        const float4 h = *reinterpret_cast<const float4*>(p3 + cg * 4);
        const float4 s0 = {a.x, e.x, f.x, h.x};
        const float4 s1 = {a.y, e.y, f.y, h.y};
        const float4 s2 = {a.z, e.z, f.z, h.z};
        const float4 s3 = {a.w, e.w, f.w, h.w};
        *reinterpret_cast<float4*>(o + (size_t)(cg * 4 + 0) * PLANE) = s0;
        *reinterpret_cast<float4*>(o + (size_t)(cg * 4 + 1) * PLANE) = s1;
        *reinterpret_cast<float4*>(o + (size_t)(cg * 4 + 2) * PLANE) = s2;
        *reinterpret_cast<float4*>(o + (size_t)(cg * 4 + 3) * PLANE) = s3;
    }
}

// ---------------------------------------------------------------------------
// Fallback (only if ws too small): direct scatter after zeroing output.
// ---------------------------------------------------------------------------
__global__ void direct_scatter_kernel(const float* __restrict__ feats,
                                      const int* __restrict__ coords, int n,
                                      float* __restrict__ out) {
    int i = blockIdx.x * blockDim.x + threadIdx.x;
    if (i >= n * Cv) return;
    int v = i >> 6;
    int c = i & 63;
    int b = coords[v * 4 + 0];
    int y = coords[v * 4 + 2];
    int x = coords[v * 4 + 3];
    out[((size_t)(b * Cv + c) * NYv + y) * NXv + x] = feats[(size_t)v * Cv + c];
}

extern "C" void kernel_launch(void* const* d_in, const int* in_sizes, int n_in,
                              void* d_out, int out_size, void* d_ws, size_t ws_size,
                              hipStream_t stream) {
    const float* t_feats  = (const float*)d_in[0];
    const int*   t_coords = (const int*)d_in[1];
    const float* s_feats  = (const float*)d_in[2];
    const int*   s_coords = (const int*)d_in[3];
    float* out = (float*)d_out;

    const int NT = in_sizes[0] / Cv;  // 16384 template voxels
    const int NS = in_sizes[2] / Cv;  // 65536 search voxels
    const size_t half = (size_t)out_size / 2;

    const size_t map_bytes = 2ull * GRID_CELLS * sizeof(int);
    const size_t ws_need   = map_bytes + 256;  // maps + zero row

    if (ws_size >= ws_need) {
        int* map = (int*)d_ws;
        const float* zero_row = (const float*)((char*)d_ws + map_bytes);

        // One memset: maps -> 0 (invalid), zero_row -> 0.0f
        hipMemsetAsync(d_ws, 0, ws_need, stream);

        build_all_kernel<<<(NT + NS + 255) / 256, 256, 0, stream>>>(
            t_coords, NT, s_coords, NS, map);

        const int gthreads = 2 * PER_TENSOR_T4;            // 428544
        gather_all_kernel<<<gthreads / 256, 256, 0, stream>>>(
            map, t_feats, s_feats, zero_row, out, half);
    } else {
        hipMemsetAsync(d_out, 0, (size_t)out_size * sizeof(float), stream);
        direct_scatter_kernel<<<(NT * Cv + 255) / 256, 256, 0, stream>>>(
            t_feats, t_coords, NT, out);
        direct_scatter_kernel<<<(NS * Cv + 255) / 256, 256, 0, stream>>>(
            s_feats, s_coords, NS, out + half);
    }
}

// Round 4
// 93.657 us; speedup vs baseline: 1.2615x; 1.1158x over previous
//
#include <hip/hip_runtime.h>

// Problem constants (match the JAX reference)
constexpr int Bv  = 4;
constexpr int NXv = 432;
constexpr int NYv = 496;
constexpr int Cv  = 64;
constexpr int PLANE = NYv * NXv;          // 214272 cells per (b) grid
constexpr int GRID_CELLS = Bv * PLANE;    // 857088 cells per tensor
constexpr int PER_TENSOR_T4 = GRID_CELLS / 4;  // 214272 threads per tensor (4 cells each)

typedef float v4f __attribute__((ext_vector_type(4)));  // native vector: legal for nontemporal builtins

// ---------------------------------------------------------------------------
// Kernel 1: fused scatter of voxel row index (i+1) into map for both tensors.
// map default is 0 (single memset covers map + zero_row). Indices unique.
// coords row layout: (b, z, y, x), z == 0.
// ---------------------------------------------------------------------------
__global__ void build_all_kernel(const int* __restrict__ t_coords, int nt,
                                 const int* __restrict__ s_coords, int ns,
                                 int* __restrict__ map) {
    int i = blockIdx.x * blockDim.x + threadIdx.x;
    if (i < nt) {
        const int4 c = reinterpret_cast<const int4*>(t_coords)[i]; // b,z,y,x
        map[(c.x * NYv + c.z) * NXv + c.w] = i + 1;
    } else if (i < nt + ns) {
        int j = i - nt;
        const int4 c = reinterpret_cast<const int4*>(s_coords)[j];
        map[GRID_CELLS + (c.x * NYv + c.z) * NXv + c.w] = j + 1;
    }
}

// ---------------------------------------------------------------------------
// Kernel 2: fused gather for BOTH output tensors.
// One thread per 4 consecutive x-cells. Per thread: pick 4 source-row
// pointers once, then 4 chunks of 16 channels. Per chunk: batch-load
// 16 float4 (4 consecutive per row = full 64B line consumed at once),
// then batch-store 16 transposed float4 with nontemporal hint.
// Tensor/batch splits land on exact wave boundaries.
// ---------------------------------------------------------------------------
__global__ __launch_bounds__(256) void gather_all_kernel(
        const int* __restrict__ map,
        const float* __restrict__ t_feats,
        const float* __restrict__ s_feats,
        const float* __restrict__ zero_row,
        float* __restrict__ out, size_t half) {
    int tid = blockIdx.x * blockDim.x + threadIdx.x;
    const int which = (tid >= PER_TENSOR_T4) ? 1 : 0;  // wave-uniform (214272 % 64 == 0)
    const int lid = tid - which * PER_TENSOR_T4;

    const int*   mp    = map + which * GRID_CELLS;
    const float* feats = which ? s_feats : t_feats;
    float*       obase = out + (which ? half : 0);

    const int g = lid * 4;                 // first cell index (b*PLANE + y*NX + x)
    const int b = lid / (PLANE / 4);       // wave-uniform (53568 % 64 == 0)

    const int4 m = *reinterpret_cast<const int4*>(mp + g);

    const float* p0 = (m.x > 0) ? feats + (size_t)(m.x - 1) * Cv : zero_row;
    const float* p1 = (m.y > 0) ? feats + (size_t)(m.y - 1) * Cv : zero_row;
    const float* p2 = (m.z > 0) ? feats + (size_t)(m.z - 1) * Cv : zero_row;
    const float* p3 = (m.w > 0) ? feats + (size_t)(m.w - 1) * Cv : zero_row;

    // out[b][c][y][x]: offset = g + b*(Cv-1)*PLANE + c*PLANE
    float* o = obase + g + (size_t)b * (Cv - 1) * PLANE;

    for (int ch = 0; ch < 4; ++ch) {       // 16 channels per chunk
        v4f r0[4], r1[4], r2[4], r3[4];
        const int cb = ch * 16;
        // ---- load phase: 16 loads, 64B contiguous per row ----
        #pragma unroll
        for (int j = 0; j < 4; ++j) {
            r0[j] = *reinterpret_cast<const v4f*>(p0 + cb + j * 4);
            r1[j] = *reinterpret_cast<const v4f*>(p1 + cb + j * 4);
            r2[j] = *reinterpret_cast<const v4f*>(p2 + cb + j * 4);
            r3[j] = *reinterpret_cast<const v4f*>(p3 + cb + j * 4);
        }
        // ---- store phase: 16 transposed nontemporal stores ----
        #pragma unroll
        for (int j = 0; j < 4; ++j) {
            const v4f s0 = {r0[j].x, r1[j].x, r2[j].x, r3[j].x};
            const v4f s1 = {r0[j].y, r1[j].y, r2[j].y, r3[j].y};
            const v4f s2 = {r0[j].z, r1[j].z, r2[j].z, r3[j].z};
            const v4f s3 = {r0[j].w, r1[j].w, r2[j].w, r3[j].w};
            __builtin_nontemporal_store(s0, reinterpret_cast<v4f*>(o + (size_t)(cb + j * 4 + 0) * PLANE));
            __builtin_nontemporal_store(s1, reinterpret_cast<v4f*>(o + (size_t)(cb + j * 4 + 1) * PLANE));
            __builtin_nontemporal_store(s2, reinterpret_cast<v4f*>(o + (size_t)(cb + j * 4 + 2) * PLANE));
            __builtin_nontemporal_store(s3, reinterpret_cast<v4f*>(o + (size_t)(cb + j * 4 + 3) * PLANE));
        }
    }
}

// ---------------------------------------------------------------------------
// Fallback (only if ws too small): direct scatter after zeroing output.
// ---------------------------------------------------------------------------
__global__ void direct_scatter_kernel(const float* __restrict__ feats,
                                      const int* __restrict__ coords, int n,
                                      float* __restrict__ out) {
    int i = blockIdx.x * blockDim.x + threadIdx.x;
    if (i >= n * Cv) return;
    int v = i >> 6;
    int c = i & 63;
    int b = coords[v * 4 + 0];
    int y = coords[v * 4 + 2];
    int x = coords[v * 4 + 3];
    out[((size_t)(b * Cv + c) * NYv + y) * NXv + x] = feats[(size_t)v * Cv + c];
}

extern "C" void kernel_launch(void* const* d_in, const int* in_sizes, int n_in,
                              void* d_out, int out_size, void* d_ws, size_t ws_size,
                              hipStream_t stream) {
    const float* t_feats  = (const float*)d_in[0];
    const int*   t_coords = (const int*)d_in[1];
    const float* s_feats  = (const float*)d_in[2];
    const int*   s_coords = (const int*)d_in[3];
    float* out = (float*)d_out;

    const int NT = in_sizes[0] / Cv;  // 16384 template voxels
    const int NS = in_sizes[2] / Cv;  // 65536 search voxels
    const size_t half = (size_t)out_size / 2;

    const size_t map_bytes = 2ull * GRID_CELLS * sizeof(int);
    const size_t ws_need   = map_bytes + 256;  // maps + zero row

    if (ws_size >= ws_need) {
        int* map = (int*)d_ws;
        const float* zero_row = (const float*)((char*)d_ws + map_bytes);

        // One memset: maps -> 0 (invalid), zero_row -> 0.0f
        (void)hipMemsetAsync(d_ws, 0, ws_need, stream);

        build_all_kernel<<<(NT + NS + 255) / 256, 256, 0, stream>>>(
            t_coords, NT, s_coords, NS, map);

        const int gthreads = 2 * PER_TENSOR_T4;            // 428544
        gather_all_kernel<<<gthreads / 256, 256, 0, stream>>>(
            map, t_feats, s_feats, zero_row, out, half);
    } else {
        (void)hipMemsetAsync(d_out, 0, (size_t)out_size * sizeof(float), stream);
        direct_scatter_kernel<<<(NT * Cv + 255) / 256, 256, 0, stream>>>(
            t_feats, t_coords, NT, out);
        direct_scatter_kernel<<<(NS * Cv + 255) / 256, 256, 0, stream>>>(
            s_feats, s_coords, NS, out + half);
    }
}